// Round 16
// baseline (961.830 us; speedup 1.0000x reference)
//
#include <hip/hip_runtime.h>
#include <hip/hip_bf16.h>

#define NTOK 8192
#define DIM  1024
#define HID  2816
#define NI   (2 * HID)          // interleaved gate|up rows per expert = 5632
#define ROWS_CAP 26880          // 8192 shared + 16384 assignments + 8*256 pad
#define TC256 104               // 32 shared 256-tiles + max 72 expert 256-tiles

typedef __bf16 bf16x8 __attribute__((ext_vector_type(8)));
typedef float  f32x4  __attribute__((ext_vector_type(4)));

__device__ __forceinline__ unsigned short f2bf(float f) {
  unsigned int x = __float_as_uint(f);
  unsigned int r = (x + 0x7fffu + ((x >> 16) & 1u)) >> 16;
  return (unsigned short)r;
}
__device__ __forceinline__ float gelu_erf(float g) {
  return 0.5f * g * (1.0f + erff(g * 0.70710678118654752f));
}

__device__ __forceinline__ void gload16(const void* g, void* l) {
  __builtin_amdgcn_global_load_lds(
      (__attribute__((address_space(1))) void*)(g),
      (__attribute__((address_space(3))) void*)(l), 16, 0, 0);
}

// ---- vectorized transpose: out[row(c)][r] = bf16(in[r][c]), 64x64 tile ----
__device__ __forceinline__ void transpose64(const float* __restrict__ in,
                                            unsigned short* __restrict__ out,
                                            int R, int C, int iloff) {
  __shared__ float t[64][65];
  int c0 = blockIdx.x * 64, r0 = blockIdx.y * 64;
  int tid = threadIdx.x;
  int lr = tid >> 4;            // 0..15
  int lc4 = (tid & 15) * 4;     // 0,4,...,60
  #pragma unroll
  for (int it = 0; it < 4; ++it) {
    int row = lr + it * 16;
    float4 v = *(const float4*)(in + (size_t)(r0 + row) * C + c0 + lc4);
    t[row][lc4] = v.x; t[row][lc4 + 1] = v.y;
    t[row][lc4 + 2] = v.z; t[row][lc4 + 3] = v.w;
  }
  __syncthreads();
  #pragma unroll
  for (int it = 0; it < 4; ++it) {
    int cloc = lr + it * 16;
    int c = c0 + cloc;
    int rowil = (iloff < 0) ? c : (((c >> 4) << 5) + (c & 15) + iloff);
    ushort4 w = make_ushort4(f2bf(t[lc4][cloc]), f2bf(t[lc4 + 1][cloc]),
                             f2bf(t[lc4 + 2][cloc]), f2bf(t[lc4 + 3][cloc]));
    *(ushort4*)(out + (size_t)rowil * R + r0 + lc4) = w;
  }
}

__global__ __launch_bounds__(256) void k_transpose_DH(
    const float* __restrict__ eg, const float* __restrict__ eu,
    const float* __restrict__ sg, const float* __restrict__ su,
    unsigned short* __restrict__ WI, unsigned short* __restrict__ SI) {
  int z = blockIdx.z;
  const float* in; unsigned short* out; int off;
  if (z < 8)        { in = eg + (size_t)z * DIM * HID;       out = WI + (size_t)z * NI * DIM; off = 0; }
  else if (z < 16)  { in = eu + (size_t)(z - 8) * DIM * HID; out = WI + (size_t)(z - 8) * NI * DIM; off = 16; }
  else if (z == 16) { in = sg; out = SI; off = 0; }
  else              { in = su; out = SI; off = 16; }
  transpose64(in, out, DIM, HID, off);
}

__global__ __launch_bounds__(256) void k_transpose_HD(
    const float* __restrict__ ed, const float* __restrict__ sd,
    unsigned short* __restrict__ WdT, unsigned short* __restrict__ SdT) {
  int z = blockIdx.z;
  const float* in; unsigned short* out;
  if (z < 8) { in = ed + (size_t)z * HID * DIM; out = WdT + (size_t)z * HID * DIM; }
  else       { in = sd; out = SdT; }
  transpose64(in, out, HID, DIM, -1);
}

// ---------------- router + fused x->bf16 cast (block-reduced stats) ----------------

__global__ __launch_bounds__(256) void k_router(const float* __restrict__ x,
                                                const float* __restrict__ gw,
                                                unsigned short* __restrict__ xb,
                                                int* __restrict__ top_idx,
                                                float* __restrict__ top_w,
                                                int* __restrict__ counts,
                                                float* __restrict__ f_cnt,
                                                float* __restrict__ P_sum) {
  __shared__ float s_p[8];
  __shared__ int   s_cnt[8];
  __shared__ int   s_f[8];
  int tid = threadIdx.x;
  if (tid < 8) { s_p[tid] = 0.f; s_cnt[tid] = 0; s_f[tid] = 0; }
  __syncthreads();

  int lane = tid & 63, wv = tid >> 6;
  float ploc[8] = {0,0,0,0,0,0,0,0};
  int   cloc[8] = {0,0,0,0,0,0,0,0};
  int   floc[8] = {0,0,0,0,0,0,0,0};

  for (int t = blockIdx.x * 4 + wv; t < NTOK; t += 2048) {
    const float4* xr = (const float4*)(x + (size_t)t * DIM) + lane * 4;
    float4 v0 = xr[0], v1 = xr[1], v2 = xr[2], v3 = xr[3];
    float xv[16] = {v0.x, v0.y, v0.z, v0.w, v1.x, v1.y, v1.z, v1.w,
                    v2.x, v2.y, v2.z, v2.w, v3.x, v3.y, v3.z, v3.w};
    ushort4* xw = (ushort4*)(xb + (size_t)t * DIM + lane * 16);
    #pragma unroll
    for (int q = 0; q < 4; ++q)
      xw[q] = make_ushort4(f2bf(xv[q * 4]), f2bf(xv[q * 4 + 1]),
                           f2bf(xv[q * 4 + 2]), f2bf(xv[q * 4 + 3]));
    float acc[8] = {0.f,0.f,0.f,0.f,0.f,0.f,0.f,0.f};
    #pragma unroll
    for (int i = 0; i < 16; ++i) {
      const float* g = gw + (size_t)(lane * 16 + i) * 8;
      #pragma unroll
      for (int e = 0; e < 8; ++e) acc[e] += xv[i] * g[e];
    }
    #pragma unroll
    for (int e = 0; e < 8; ++e) {
      #pragma unroll
      for (int off = 32; off > 0; off >>= 1)
        acc[e] += __shfl_xor(acc[e], off, 64);
    }
    if (lane == 0) {
      int i1 = 0; float l1 = acc[0];
      #pragma unroll
      for (int e = 1; e < 8; ++e) if (acc[e] > l1) { l1 = acc[e]; i1 = e; }
      int i2 = -1; float l2 = -3.0e38f;
      #pragma unroll
      for (int e = 0; e < 8; ++e) if (e != i1 && acc[e] > l2) { l2 = acc[e]; i2 = e; }
      float e2 = expf(l2 - l1);
      float inv12 = 1.0f / (1.0f + e2);
      top_idx[2 * t] = i1; top_idx[2 * t + 1] = i2;
      top_w[2 * t] = inv12; top_w[2 * t + 1] = e2 * inv12;
      float s = 0.f, p[8];
      #pragma unroll
      for (int e = 0; e < 8; ++e) { p[e] = expf(acc[e] - l1); s += p[e]; }
      float invs = 1.0f / s;
      #pragma unroll
      for (int e = 0; e < 8; ++e) {
        ploc[e] += p[e] * invs;
        cloc[e] += (e == i1) + (e == i2);
        floc[e] += (e == i1);
      }
    }
  }
  if (lane == 0) {
    #pragma unroll
    for (int e = 0; e < 8; ++e) {
      atomicAdd(&s_p[e], ploc[e]);
      atomicAdd(&s_cnt[e], cloc[e]);
      atomicAdd(&s_f[e], floc[e]);
    }
  }
  __syncthreads();
  if (tid < 8) {
    atomicAdd(&P_sum[tid], s_p[tid]);
    atomicAdd(&counts[tid], s_cnt[tid]);
    atomicAdd(&f_cnt[tid], (float)s_f[tid]);
  }
}

// ---------------- segment setup (256-row padding) / scatter ----------------

__global__ __launch_bounds__(256) void k_setup(const int* __restrict__ counts,
                                               int* __restrict__ cursors,
                                               int* __restrict__ te256,
                                               int* __restrict__ perm,
                                               float* __restrict__ wrow) {
  int t = threadIdx.x;
  for (int r = t; r < ROWS_CAP; r += 256) {
    perm[r] = (r < NTOK) ? r : 0;
    wrow[r] = (r < NTOK) ? 1.0f : 0.0f;
  }
  if (t == 0) {
    int so[8], pe[8];
    int cur = NTOK;
    for (int e = 0; e < 8; ++e) {
      so[e] = cur;
      pe[e] = ((counts[e] + 255) >> 8) << 8;     // pad to 256 rows
      cur += pe[e];
    }
    for (int e = 0; e < 8; ++e) cursors[e] = so[e];
    for (int T = 0; T < TC256; ++T) {
      int r0 = T << 8;
      int ex;
      if (T < NTOK / 256) ex = 8;                // shared expert
      else if (r0 < cur) {
        ex = 0;
        for (int e = 0; e < 8; ++e) if (r0 >= so[e] && r0 < so[e] + pe[e]) ex = e;
      } else ex = -1;
      te256[T] = ex;
    }
  }
}

__global__ __launch_bounds__(256) void k_scatter(const int* __restrict__ top_idx,
                                                 const float* __restrict__ top_w,
                                                 int* __restrict__ cursors,
                                                 int* __restrict__ perm,
                                                 float* __restrict__ wrow) {
  int i = blockIdx.x * 256 + threadIdx.x;
  if (i < NTOK * 2) {
    int e = top_idx[i];
    float w = top_w[i];
    int slot = atomicAdd(&cursors[e], 1);
    perm[slot] = i >> 1;
    wrow[slot] = w;
  }
}

// ---------------- stage A: h = gelu(x@gate) * (x@up) -------------------------
// 256-row tiles, 512 threads (8 waves 2x4), interleaved gate|up B.
// 4-phase interleaved schedule (round-15-proven). XOR-swizzled LDS.

__global__ __launch_bounds__(512) void k_stageA(const unsigned short* __restrict__ xb,
    const unsigned short* __restrict__ WI, const unsigned short* __restrict__ SI,
    const int* __restrict__ perm, const int* __restrict__ te256,
    unsigned short* __restrict__ h, int T0, int row_base) {
  int T = T0 + blockIdx.y;
  int e = te256[T];
  if (e < 0) return;
  const unsigned short* B = (e < 8) ? WI + (size_t)e * NI * DIM : SI;
  int rows0 = T * 256;
  int c0i = blockIdx.x * 256;     // interleaved-col base

  __shared__ unsigned short As[2][256 * 64];   // 32 KB each
  __shared__ unsigned short Bs[2][256 * 64];

  int tid = threadIdx.x, lane = tid & 63, w = tid >> 6;
  int wr = w >> 2, wc = w & 3;
  int rlo = lane >> 3;
  int koff = ((lane & 7) ^ rlo) * 8;           // pre-swizzled source column
  int fr = lane & 15;
  int kby0 = ((lane >> 4) * 16) ^ ((lane & 7) << 4);
  int kby1 = (64 + (lane >> 4) * 16) ^ ((lane & 7) << 4);

  int prow[4];
  #pragma unroll
  for (int i = 0; i < 4; ++i) prow[i] = perm[rows0 + i * 64 + w * 8 + rlo];
  const unsigned short* bsrc[4];
  #pragma unroll
  for (int i = 0; i < 4; ++i)
    bsrc[i] = B + (size_t)(c0i + i * 64 + w * 8 + rlo) * DIM + koff;

  f32x4 acc[8][4] = {};

  #pragma unroll
  for (int i = 0; i < 4; ++i)
    gload16(xb + (size_t)prow[i] * DIM + koff, (char*)As[0] + (i * 64 + w * 8) * 128);
  #pragma unroll
  for (int i = 0; i < 4; ++i)
    gload16(bsrc[i], (char*)Bs[0] + (i * 64 + w * 8) * 128);
  asm volatile("s_waitcnt vmcnt(0)" ::: "memory");
  __builtin_amdgcn_s_barrier();
  __builtin_amdgcn_sched_barrier(0);

  int cur = 0;
  for (int kb = 0; kb < DIM / 64; ++kb) {
    const char* Ab = (const char*)As[cur];
    const char* Bb = (const char*)Bs[cur];
    char* An = (char*)As[cur ^ 1];
    char* Bn = (char*)Bs[cur ^ 1];
    int k1 = (kb + 1) * 64;
    bool pf = (kb < DIM / 64 - 1);
    bf16x8 bfr[4][2];

    #pragma unroll
    for (int q = 0; q < 4; ++q) {
      bf16x8 a[2][2];
      #pragma unroll
      for (int m = 0; m < 2; ++m) {
        const char* ar = Ab + (wr * 128 + (2 * q + m) * 16 + fr) * 128;
        a[m][0] = *(const bf16x8*)(ar + kby0);
        a[m][1] = *(const bf16x8*)(ar + kby1);
      }
      if (q == 0) {
        #pragma unroll
        for (int ni = 0; ni < 4; ++ni) {
          const char* br = Bb + (wc * 64 + ni * 16 + fr) * 128;
          bfr[ni][0] = *(const bf16x8*)(br + kby0);
          bfr[ni][1] = *(const bf16x8*)(br + kby1);
        }
      }
      if (pf) {
        if (q == 0) {
          gload16(xb + (size_t)prow[0] * DIM + k1 + koff, An + (0 * 64 + w * 8) * 128);
          gload16(xb + (size_t)prow[1] * DIM + k1 + koff, An + (1 * 64 + w * 8) * 128);
        } else if (q == 1) {
          gload16(xb + (size_t)prow[2] * DIM + k1 + koff, An + (2 * 64 + w * 8) * 128);
          gload16(xb + (size_t)prow[3] * DIM + k1 + koff, An + (3 * 64 + w * 8) * 128);
        } else if (q == 2) {
          gload16(bsrc[0] + k1, Bn + (0 * 64 + w * 8) * 128);
          gload16(bsrc[1] + k1, Bn + (1 * 64 + w * 8) * 128);
        } else {
          gload16(bsrc[2] + k1, Bn + (2 * 64 + w * 8) * 128);
          gload16(bsrc[3] + k1, Bn + (3 * 64 + w * 8) * 128);
        }
      }
      __builtin_amdgcn_s_barrier();
      __builtin_amdgcn_s_setprio(1);
      #pragma unroll
      for (int kk = 0; kk < 2; ++kk) {
        #pragma unroll
        for (int m = 0; m < 2; ++m) {
          #pragma unroll
          for (int ni = 0; ni < 4; ++ni)
            acc[2 * q + m][ni] = __builtin_amdgcn_mfma_f32_16x16x32_bf16(
                a[m][kk], bfr[ni][kk], acc[2 * q + m][ni], 0, 0, 0);
        }
      }
      __builtin_amdgcn_s_setprio(0);
      if (q < 3) {
        __builtin_amdgcn_s_barrier();
      } else {
        asm volatile("s_waitcnt vmcnt(0)" ::: "memory");
        __builtin_amdgcn_s_barrier();
        __builtin_amdgcn_sched_barrier(0);
      }
    }
    cur ^= 1;
  }

  #pragma unroll
  for (int mi = 0; mi < 8; ++mi) {
    #pragma unroll
    for (int p = 0; p < 2; ++p) {
      #pragma unroll
      for (int j = 0; j < 4; ++j) {
        int rg = rows0 - row_base + wr * 128 + mi * 16 + (lane >> 4) * 4 + j;
        int cg = blockIdx.x * 128 + wc * 32 + p * 16 + fr;
        float g = acc[mi][2 * p][j];
        float u = acc[mi][2 * p + 1][j];
        h[(size_t)rg * HID + cg] = f2bf(gelu_erf(g) * u);
      }
    }
  }
}

// ---------------- stage B: out(f32) = / += w * (h @ downT) ----------------
// SAME 256-tile 4-phase structure as stage A (no gather, single B matrix).

template <bool STORE>
__global__ __launch_bounds__(512) void k_stageB(const unsigned short* __restrict__ h,
    const unsigned short* __restrict__ WdT, const unsigned short* __restrict__ SdT,
    const int* __restrict__ perm, const float* __restrict__ wrow,
    const int* __restrict__ te256,
    float* __restrict__ out, int T0, int row_base) {
  int T = T0 + blockIdx.y;
  int e = te256[T];
  if (e < 0) return;
  const unsigned short* Bd = (e < 8) ? WdT + (size_t)e * DIM * HID : SdT;
  int rows0 = T * 256;
  int n0 = blockIdx.x * 256;

  __shared__ unsigned short As[2][256 * 64];
  __shared__ unsigned short Bs[2][256 * 64];

  int tid = threadIdx.x, lane = tid & 63, w = tid >> 6;
  int wr = w >> 2, wc = w & 3;
  int rlo = lane >> 3;
  int koff = ((lane & 7) ^ rlo) * 8;
  int fr = lane & 15;
  int kby0 = ((lane >> 4) * 16) ^ ((lane & 7) << 4);
  int kby1 = (64 + (lane >> 4) * 16) ^ ((lane & 7) << 4);

  const unsigned short* asrc[4];
  #pragma unroll
  for (int i = 0; i < 4; ++i)
    asrc[i] = h + (size_t)(rows0 - row_base + i * 64 + w * 8 + rlo) * HID + koff;
  const unsigned short* bsrc[4];
  #pragma unroll
  for (int i = 0; i < 4; ++i)
    bsrc[i] = Bd + (size_t)(n0 + i * 64 + w * 8 + rlo) * HID + koff;

  f32x4 acc[8][4] = {};

  #pragma unroll
  for (int i = 0; i < 4; ++i)
    gload16(asrc[i], (char*)As[0] + (i * 64 + w * 8) * 128);
  #pragma unroll
  for (int i = 0; i < 4; ++i)
    gload16(bsrc[i], (char*)Bs[0] + (i * 64 + w * 8) * 128);
  asm volatile("s_waitcnt vmcnt(0)" ::: "memory");
  __builtin_amdgcn_s_barrier();
  __builtin_amdgcn_sched_barrier(0);

  int cur = 0;
  for (int kb = 0; kb < HID / 64; ++kb) {
    const char* Ab = (const char*)As[cur];
    const char* Bb = (const char*)Bs[cur];
    char* An = (char*)As[cur ^ 1];
    char* Bn = (char*)Bs[cur ^ 1];
    int k1 = (kb + 1) * 64;
    bool pf = (kb < HID / 64 - 1);
    bf16x8 bfr[4][2];

    #pragma unroll
    for (int q = 0; q < 4; ++q) {
      bf16x8 a[2][2];
      #pragma unroll
      for (int m = 0; m < 2; ++m) {
        const char* ar = Ab + (wr * 128 + (2 * q + m) * 16 + fr) * 128;
        a[m][0] = *(const bf16x8*)(ar + kby0);
        a[m][1] = *(const bf16x8*)(ar + kby1);
      }
      if (q == 0) {
        #pragma unroll
        for (int ni = 0; ni < 4; ++ni) {
          const char* br = Bb + (wc * 64 + ni * 16 + fr) * 128;
          bfr[ni][0] = *(const bf16x8*)(br + kby0);
          bfr[ni][1] = *(const bf16x8*)(br + kby1);
        }
      }
      if (pf) {
        if (q == 0) {
          gload16(asrc[0] + k1, An + (0 * 64 + w * 8) * 128);
          gload16(asrc[1] + k1, An + (1 * 64 + w * 8) * 128);
        } else if (q == 1) {
          gload16(asrc[2] + k1, An + (2 * 64 + w * 8) * 128);
          gload16(asrc[3] + k1, An + (3 * 64 + w * 8) * 128);
        } else if (q == 2) {
          gload16(bsrc[0] + k1, Bn + (0 * 64 + w * 8) * 128);
          gload16(bsrc[1] + k1, Bn + (1 * 64 + w * 8) * 128);
        } else {
          gload16(bsrc[2] + k1, Bn + (2 * 64 + w * 8) * 128);
          gload16(bsrc[3] + k1, Bn + (3 * 64 + w * 8) * 128);
        }
      }
      __builtin_amdgcn_s_barrier();
      __builtin_amdgcn_s_setprio(1);
      #pragma unroll
      for (int kk = 0; kk < 2; ++kk) {
        #pragma unroll
        for (int m = 0; m < 2; ++m) {
          #pragma unroll
          for (int ni = 0; ni < 4; ++ni)
            acc[2 * q + m][ni] = __builtin_amdgcn_mfma_f32_16x16x32_bf16(
                a[m][kk], bfr[ni][kk], acc[2 * q + m][ni], 0, 0, 0);
        }
      }
      __builtin_amdgcn_s_setprio(0);
      if (q < 3) {
        __builtin_amdgcn_s_barrier();
      } else {
        asm volatile("s_waitcnt vmcnt(0)" ::: "memory");
        __builtin_amdgcn_s_barrier();
        __builtin_amdgcn_sched_barrier(0);
      }
    }
    cur ^= 1;
  }

  #pragma unroll
  for (int mi = 0; mi < 8; ++mi) {
    #pragma unroll
    for (int j = 0; j < 4; ++j) {
      int rl = wr * 128 + mi * 16 + (lane >> 4) * 4 + j;
      int token = perm[rows0 + rl];
      float wt = wrow[rows0 + rl];
      #pragma unroll
      for (int ni = 0; ni < 4; ++ni) {
        int col = n0 + wc * 64 + ni * 16 + fr;
        if (STORE) out[(size_t)token * DIM + col] = wt * acc[mi][ni][j];
        else atomicAdd(&out[(size_t)token * DIM + col], wt * acc[mi][ni][j]);
      }
    }
  }
}

// ---------------- aux loss (f32) ----------------

__global__ void k_aux(const float* __restrict__ f_cnt, const float* __restrict__ P_sum,
                      float* __restrict__ aux_out) {
  if (threadIdx.x == 0 && blockIdx.x == 0) {
    float a = 0.f;
    #pragma unroll
    for (int e = 0; e < 8; ++e) a += f_cnt[e] * P_sum[e];
    a *= 0.01f * 8.f / ((float)NTOK * (float)NTOK);
    aux_out[0] = a;
  }
}

// ---------------- launch ----------------

extern "C" void kernel_launch(void* const* d_in, const int* in_sizes, int n_in,
                              void* d_out, int out_size, void* d_ws, size_t ws_size,
                              hipStream_t stream) {
  const float* x  = (const float*)d_in[0];
  const float* gw = (const float*)d_in[1];
  const float* eg = (const float*)d_in[2];
  const float* eu = (const float*)d_in[3];
  const float* ed = (const float*)d_in[4];
  const float* sg = (const float*)d_in[5];
  const float* su = (const float*)d_in[6];
  const float* sd = (const float*)d_in[7];
  float* out = (float*)d_out;

  char* ws = (char*)d_ws;
  size_t off = 0;
  auto take = [&](size_t sz) { size_t o = off; off += (sz + 255) & ~(size_t)255; return o; };
  const size_t OFF_XB   = take((size_t)NTOK * DIM * 2);
  const size_t OFF_WI   = take((size_t)8 * NI * DIM * 2);   // interleaved gate|up
  const size_t OFF_SI   = take((size_t)NI * DIM * 2);
  const size_t OFF_WDT  = take((size_t)8 * HID * DIM * 2);
  const size_t OFF_SDT  = take((size_t)HID * DIM * 2);
  const size_t OFF_TI   = take((size_t)NTOK * 2 * 4);
  const size_t OFF_TW   = take((size_t)NTOK * 2 * 4);
  const size_t OFF_PERM = take((size_t)ROWS_CAP * 4);
  const size_t OFF_WROW = take((size_t)ROWS_CAP * 4);
  const size_t OFF_STATS= take(256);
  const size_t OFF_CURS = take(256);
  const size_t OFF_TE2  = take(TC256 * 4);
  const size_t OFF_H    = off;   // h-buffer takes ALL remaining space

  const size_t TILE_H_BYTES = (size_t)256 * HID * 2;   // per 256-tile
  size_t avail = (ws_size > OFF_H) ? (ws_size - OFF_H) : 0;
  int G = (int)((avail / TILE_H_BYTES < (size_t)TC256) ? (avail / TILE_H_BYTES) : (size_t)TC256);
  if (G < 1) return;

  unsigned short* xb  = (unsigned short*)(ws + OFF_XB);
  unsigned short* WI  = (unsigned short*)(ws + OFF_WI);
  unsigned short* SI  = (unsigned short*)(ws + OFF_SI);
  unsigned short* WdT = (unsigned short*)(ws + OFF_WDT);
  unsigned short* SdT = (unsigned short*)(ws + OFF_SDT);
  int* top_idx        = (int*)(ws + OFF_TI);
  float* top_w        = (float*)(ws + OFF_TW);
  int* perm           = (int*)(ws + OFF_PERM);
  float* wrow         = (float*)(ws + OFF_WROW);
  int* counts         = (int*)(ws + OFF_STATS);
  float* f_cnt        = (float*)(ws + OFF_STATS + 32);
  float* P_sum        = (float*)(ws + OFF_STATS + 64);
  int* cursors        = (int*)(ws + OFF_CURS);
  int* te256          = (int*)(ws + OFF_TE2);
  unsigned short* hbuf = (unsigned short*)(ws + OFF_H);

  hipMemsetAsync(ws + OFF_STATS, 0, 256, stream);

  k_transpose_DH<<<dim3(HID / 64, DIM / 64, 18), 256, 0, stream>>>(
      eg, eu, sg, su, WI, SI);
  k_transpose_HD<<<dim3(DIM / 64, HID / 64, 9), 256, 0, stream>>>(
      ed, sd, WdT, SdT);

  k_router<<<512, 256, 0, stream>>>(x, gw, xb, top_idx, top_w, counts, f_cnt, P_sum);
  k_setup<<<1, 256, 0, stream>>>(counts, cursors, te256, perm, wrow);
  k_scatter<<<NTOK * 2 / 256, 256, 0, stream>>>(top_idx, top_w, cursors, perm, wrow);

  for (int T0 = 0; T0 < TC256; T0 += G) {
    int nt = (TC256 - T0 < G) ? (TC256 - T0) : G;
    int row_base = T0 * 256;
    k_stageA<<<dim3(NI / 256, nt), 512, 0, stream>>>(xb, WI, SI, perm, te256,
                                                     hbuf, T0, row_base);
    int ns = 0;
    if (T0 < 32) { ns = 32 - T0; if (ns > nt) ns = nt; }
    int ne = nt - ns;
    if (ns > 0)
      k_stageB<true><<<dim3(DIM / 256, ns), 512, 0, stream>>>(hbuf, WdT, SdT, perm, wrow,
                                                              te256, out, T0, row_base);
    if (ne > 0)
      k_stageB<false><<<dim3(DIM / 256, ne), 512, 0, stream>>>(hbuf, WdT, SdT, perm, wrow,
                                                               te256, out, T0 + ns, row_base);
  }

  k_aux<<<1, 64, 0, stream>>>(f_cnt, P_sum, out + (size_t)NTOK * DIM);
}

// Round 17
// 915.293 us; speedup vs baseline: 1.0508x; 1.0508x over previous
//
#include <hip/hip_runtime.h>
#include <hip/hip_bf16.h>

#define NTOK 8192
#define DIM  1024
#define HID  2816
#define NI   (2 * HID)          // interleaved gate|up rows per expert = 5632
#define ROWS_CAP 26880          // 8192 shared + 16384 assignments + 8*256 pad
#define TC256 104               // 32 shared 256-tiles + max 72 expert 256-tiles
#define TC128 208               // same in 128-half-tiles

typedef __bf16 bf16x8 __attribute__((ext_vector_type(8)));
typedef float  f32x4  __attribute__((ext_vector_type(4)));

__device__ __forceinline__ unsigned short f2bf(float f) {
  unsigned int x = __float_as_uint(f);
  unsigned int r = (x + 0x7fffu + ((x >> 16) & 1u)) >> 16;
  return (unsigned short)r;
}
__device__ __forceinline__ float gelu_erf(float g) {
  return 0.5f * g * (1.0f + erff(g * 0.70710678118654752f));
}

__device__ __forceinline__ void gload16(const void* g, void* l) {
  __builtin_amdgcn_global_load_lds(
      (__attribute__((address_space(1))) void*)(g),
      (__attribute__((address_space(3))) void*)(l), 16, 0, 0);
}

// ---- vectorized transpose: out[row(c)][r] = bf16(in[r][c]), 64x64 tile ----
__device__ __forceinline__ void transpose64(const float* __restrict__ in,
                                            unsigned short* __restrict__ out,
                                            int R, int C, int iloff) {
  __shared__ float t[64][65];
  int c0 = blockIdx.x * 64, r0 = blockIdx.y * 64;
  int tid = threadIdx.x;
  int lr = tid >> 4;            // 0..15
  int lc4 = (tid & 15) * 4;     // 0,4,...,60
  #pragma unroll
  for (int it = 0; it < 4; ++it) {
    int row = lr + it * 16;
    float4 v = *(const float4*)(in + (size_t)(r0 + row) * C + c0 + lc4);
    t[row][lc4] = v.x; t[row][lc4 + 1] = v.y;
    t[row][lc4 + 2] = v.z; t[row][lc4 + 3] = v.w;
  }
  __syncthreads();
  #pragma unroll
  for (int it = 0; it < 4; ++it) {
    int cloc = lr + it * 16;
    int c = c0 + cloc;
    int rowil = (iloff < 0) ? c : (((c >> 4) << 5) + (c & 15) + iloff);
    ushort4 w = make_ushort4(f2bf(t[lc4][cloc]), f2bf(t[lc4 + 1][cloc]),
                             f2bf(t[lc4 + 2][cloc]), f2bf(t[lc4 + 3][cloc]));
    *(ushort4*)(out + (size_t)rowil * R + r0 + lc4) = w;
  }
}

__global__ __launch_bounds__(256) void k_transpose_DH(
    const float* __restrict__ eg, const float* __restrict__ eu,
    const float* __restrict__ sg, const float* __restrict__ su,
    unsigned short* __restrict__ WI, unsigned short* __restrict__ SI) {
  int z = blockIdx.z;
  const float* in; unsigned short* out; int off;
  if (z < 8)        { in = eg + (size_t)z * DIM * HID;       out = WI + (size_t)z * NI * DIM; off = 0; }
  else if (z < 16)  { in = eu + (size_t)(z - 8) * DIM * HID; out = WI + (size_t)(z - 8) * NI * DIM; off = 16; }
  else if (z == 16) { in = sg; out = SI; off = 0; }
  else              { in = su; out = SI; off = 16; }
  transpose64(in, out, DIM, HID, off);
}

__global__ __launch_bounds__(256) void k_transpose_HD(
    const float* __restrict__ ed, const float* __restrict__ sd,
    unsigned short* __restrict__ WdT, unsigned short* __restrict__ SdT) {
  int z = blockIdx.z;
  const float* in; unsigned short* out;
  if (z < 8) { in = ed + (size_t)z * HID * DIM; out = WdT + (size_t)z * HID * DIM; }
  else       { in = sd; out = SdT; }
  transpose64(in, out, HID, DIM, -1);
}

// ---------------- router + fused x->bf16 cast (block-reduced stats) ----------------

__global__ __launch_bounds__(256) void k_router(const float* __restrict__ x,
                                                const float* __restrict__ gw,
                                                unsigned short* __restrict__ xb,
                                                int* __restrict__ top_idx,
                                                float* __restrict__ top_w,
                                                int* __restrict__ counts,
                                                float* __restrict__ f_cnt,
                                                float* __restrict__ P_sum) {
  __shared__ float s_p[8];
  __shared__ int   s_cnt[8];
  __shared__ int   s_f[8];
  int tid = threadIdx.x;
  if (tid < 8) { s_p[tid] = 0.f; s_cnt[tid] = 0; s_f[tid] = 0; }
  __syncthreads();

  int lane = tid & 63, wv = tid >> 6;
  float ploc[8] = {0,0,0,0,0,0,0,0};
  int   cloc[8] = {0,0,0,0,0,0,0,0};
  int   floc[8] = {0,0,0,0,0,0,0,0};

  for (int t = blockIdx.x * 4 + wv; t < NTOK; t += 2048) {
    const float4* xr = (const float4*)(x + (size_t)t * DIM) + lane * 4;
    float4 v0 = xr[0], v1 = xr[1], v2 = xr[2], v3 = xr[3];
    float xv[16] = {v0.x, v0.y, v0.z, v0.w, v1.x, v1.y, v1.z, v1.w,
                    v2.x, v2.y, v2.z, v2.w, v3.x, v3.y, v3.z, v3.w};
    ushort4* xw = (ushort4*)(xb + (size_t)t * DIM + lane * 16);
    #pragma unroll
    for (int q = 0; q < 4; ++q)
      xw[q] = make_ushort4(f2bf(xv[q * 4]), f2bf(xv[q * 4 + 1]),
                           f2bf(xv[q * 4 + 2]), f2bf(xv[q * 4 + 3]));
    float acc[8] = {0.f,0.f,0.f,0.f,0.f,0.f,0.f,0.f};
    #pragma unroll
    for (int i = 0; i < 16; ++i) {
      const float* g = gw + (size_t)(lane * 16 + i) * 8;
      #pragma unroll
      for (int e = 0; e < 8; ++e) acc[e] += xv[i] * g[e];
    }
    #pragma unroll
    for (int e = 0; e < 8; ++e) {
      #pragma unroll
      for (int off = 32; off > 0; off >>= 1)
        acc[e] += __shfl_xor(acc[e], off, 64);
    }
    if (lane == 0) {
      int i1 = 0; float l1 = acc[0];
      #pragma unroll
      for (int e = 1; e < 8; ++e) if (acc[e] > l1) { l1 = acc[e]; i1 = e; }
      int i2 = -1; float l2 = -3.0e38f;
      #pragma unroll
      for (int e = 0; e < 8; ++e) if (e != i1 && acc[e] > l2) { l2 = acc[e]; i2 = e; }
      float e2 = expf(l2 - l1);
      float inv12 = 1.0f / (1.0f + e2);
      top_idx[2 * t] = i1; top_idx[2 * t + 1] = i2;
      top_w[2 * t] = inv12; top_w[2 * t + 1] = e2 * inv12;
      float s = 0.f, p[8];
      #pragma unroll
      for (int e = 0; e < 8; ++e) { p[e] = expf(acc[e] - l1); s += p[e]; }
      float invs = 1.0f / s;
      #pragma unroll
      for (int e = 0; e < 8; ++e) {
        ploc[e] += p[e] * invs;
        cloc[e] += (e == i1) + (e == i2);
        floc[e] += (e == i1);
      }
    }
  }
  if (lane == 0) {
    #pragma unroll
    for (int e = 0; e < 8; ++e) {
      atomicAdd(&s_p[e], ploc[e]);
      atomicAdd(&s_cnt[e], cloc[e]);
      atomicAdd(&s_f[e], floc[e]);
    }
  }
  __syncthreads();
  if (tid < 8) {
    atomicAdd(&P_sum[tid], s_p[tid]);
    atomicAdd(&counts[tid], s_cnt[tid]);
    atomicAdd(&f_cnt[tid], (float)s_f[tid]);
  }
}

// ---------------- segment setup (256-row padding) / scatter ----------------

__global__ __launch_bounds__(256) void k_setup(const int* __restrict__ counts,
                                               int* __restrict__ cursors,
                                               int* __restrict__ te256,
                                               int* __restrict__ te128,
                                               int* __restrict__ perm,
                                               float* __restrict__ wrow) {
  int t = threadIdx.x;
  for (int r = t; r < ROWS_CAP; r += 256) {
    perm[r] = (r < NTOK) ? r : 0;
    wrow[r] = (r < NTOK) ? 1.0f : 0.0f;
  }
  if (t == 0) {
    int so[8], pe[8];
    int cur = NTOK;
    for (int e = 0; e < 8; ++e) {
      so[e] = cur;
      pe[e] = ((counts[e] + 255) >> 8) << 8;     // pad to 256 rows
      cur += pe[e];
    }
    for (int e = 0; e < 8; ++e) cursors[e] = so[e];
    for (int T = 0; T < TC256; ++T) {
      int r0 = T << 8;
      int ex;
      if (T < NTOK / 256) ex = 8;                // shared expert
      else if (r0 < cur) {
        ex = 0;
        for (int e = 0; e < 8; ++e) if (r0 >= so[e] && r0 < so[e] + pe[e]) ex = e;
      } else ex = -1;
      te256[T] = ex;
    }
    for (int ht = 0; ht < TC128; ++ht) {
      int r0 = ht << 7;
      int ex;
      if (ht < NTOK / 128) ex = 8;
      else if (r0 < cur) {
        ex = 0;
        for (int e = 0; e < 8; ++e) if (r0 >= so[e] && r0 < so[e] + pe[e]) ex = e;
      } else ex = -1;
      te128[ht] = ex;
    }
  }
}

__global__ __launch_bounds__(256) void k_scatter(const int* __restrict__ top_idx,
                                                 const float* __restrict__ top_w,
                                                 int* __restrict__ cursors,
                                                 int* __restrict__ perm,
                                                 float* __restrict__ wrow) {
  int i = blockIdx.x * 256 + threadIdx.x;
  if (i < NTOK * 2) {
    int e = top_idx[i];
    float w = top_w[i];
    int slot = atomicAdd(&cursors[e], 1);
    perm[slot] = i >> 1;
    wrow[slot] = w;
  }
}

// ---------------- stage A: h = gelu(x@gate) * (x@up) -------------------------
// 256-row tiles, 512 threads (8 waves 2x4), interleaved gate|up B.
// 4-phase interleaved schedule; ALL 8 prefetches issued in phases 0-1 so the
// last load gets ~3 MFMA phases of cover before the boundary drain.

__global__ __launch_bounds__(512) void k_stageA(const unsigned short* __restrict__ xb,
    const unsigned short* __restrict__ WI, const unsigned short* __restrict__ SI,
    const int* __restrict__ perm, const int* __restrict__ te256,
    unsigned short* __restrict__ h, int T0, int row_base) {
  int T = T0 + blockIdx.y;
  int e = te256[T];
  if (e < 0) return;
  const unsigned short* B = (e < 8) ? WI + (size_t)e * NI * DIM : SI;
  int rows0 = T * 256;
  int c0i = blockIdx.x * 256;     // interleaved-col base

  __shared__ unsigned short As[2][256 * 64];   // 32 KB each
  __shared__ unsigned short Bs[2][256 * 64];

  int tid = threadIdx.x, lane = tid & 63, w = tid >> 6;
  int wr = w >> 2, wc = w & 3;
  int rlo = lane >> 3;
  int koff = ((lane & 7) ^ rlo) * 8;           // pre-swizzled source column
  int fr = lane & 15;
  int kby0 = ((lane >> 4) * 16) ^ ((lane & 7) << 4);
  int kby1 = (64 + (lane >> 4) * 16) ^ ((lane & 7) << 4);

  int prow[4];
  #pragma unroll
  for (int i = 0; i < 4; ++i) prow[i] = perm[rows0 + i * 64 + w * 8 + rlo];
  const unsigned short* bsrc[4];
  #pragma unroll
  for (int i = 0; i < 4; ++i)
    bsrc[i] = B + (size_t)(c0i + i * 64 + w * 8 + rlo) * DIM + koff;

  f32x4 acc[8][4] = {};

  #pragma unroll
  for (int i = 0; i < 4; ++i)
    gload16(xb + (size_t)prow[i] * DIM + koff, (char*)As[0] + (i * 64 + w * 8) * 128);
  #pragma unroll
  for (int i = 0; i < 4; ++i)
    gload16(bsrc[i], (char*)Bs[0] + (i * 64 + w * 8) * 128);
  asm volatile("s_waitcnt vmcnt(0)" ::: "memory");
  __builtin_amdgcn_s_barrier();
  __builtin_amdgcn_sched_barrier(0);

  int cur = 0;
  for (int kb = 0; kb < DIM / 64; ++kb) {
    const char* Ab = (const char*)As[cur];
    const char* Bb = (const char*)Bs[cur];
    char* An = (char*)As[cur ^ 1];
    char* Bn = (char*)Bs[cur ^ 1];
    int k1 = (kb + 1) * 64;
    bool pf = (kb < DIM / 64 - 1);
    bf16x8 bfr[4][2];

    #pragma unroll
    for (int q = 0; q < 4; ++q) {
      bf16x8 a[2][2];
      #pragma unroll
      for (int m = 0; m < 2; ++m) {
        const char* ar = Ab + (wr * 128 + (2 * q + m) * 16 + fr) * 128;
        a[m][0] = *(const bf16x8*)(ar + kby0);
        a[m][1] = *(const bf16x8*)(ar + kby1);
      }
      if (q == 0) {
        #pragma unroll
        for (int ni = 0; ni < 4; ++ni) {
          const char* br = Bb + (wc * 64 + ni * 16 + fr) * 128;
          bfr[ni][0] = *(const bf16x8*)(br + kby0);
          bfr[ni][1] = *(const bf16x8*)(br + kby1);
        }
      }
      // prefetch: all 8 loads in phases 0-1 (issue-early, drain-late)
      if (pf) {
        if (q == 0) {
          gload16(xb + (size_t)prow[0] * DIM + k1 + koff, An + (0 * 64 + w * 8) * 128);
          gload16(xb + (size_t)prow[1] * DIM + k1 + koff, An + (1 * 64 + w * 8) * 128);
          gload16(bsrc[0] + k1, Bn + (0 * 64 + w * 8) * 128);
          gload16(bsrc[1] + k1, Bn + (1 * 64 + w * 8) * 128);
        } else if (q == 1) {
          gload16(xb + (size_t)prow[2] * DIM + k1 + koff, An + (2 * 64 + w * 8) * 128);
          gload16(xb + (size_t)prow[3] * DIM + k1 + koff, An + (3 * 64 + w * 8) * 128);
          gload16(bsrc[2] + k1, Bn + (2 * 64 + w * 8) * 128);
          gload16(bsrc[3] + k1, Bn + (3 * 64 + w * 8) * 128);
        }
      }
      __builtin_amdgcn_s_barrier();
      __builtin_amdgcn_s_setprio(1);
      #pragma unroll
      for (int kk = 0; kk < 2; ++kk) {
        #pragma unroll
        for (int m = 0; m < 2; ++m) {
          #pragma unroll
          for (int ni = 0; ni < 4; ++ni)
            acc[2 * q + m][ni] = __builtin_amdgcn_mfma_f32_16x16x32_bf16(
                a[m][kk], bfr[ni][kk], acc[2 * q + m][ni], 0, 0, 0);
        }
      }
      __builtin_amdgcn_s_setprio(0);
      if (q < 3) {
        __builtin_amdgcn_s_barrier();
      } else {
        asm volatile("s_waitcnt vmcnt(0)" ::: "memory");
        __builtin_amdgcn_s_barrier();
        __builtin_amdgcn_sched_barrier(0);
      }
    }
    cur ^= 1;
  }

  #pragma unroll
  for (int mi = 0; mi < 8; ++mi) {
    #pragma unroll
    for (int p = 0; p < 2; ++p) {
      #pragma unroll
      for (int j = 0; j < 4; ++j) {
        int rg = rows0 - row_base + wr * 128 + mi * 16 + (lane >> 4) * 4 + j;
        int cg = blockIdx.x * 128 + wc * 32 + p * 16 + fr;
        float g = acc[mi][2 * p][j];
        float u = acc[mi][2 * p + 1][j];
        h[(size_t)rg * HID + cg] = f2bf(gelu_erf(g) * u);
      }
    }
  }
}

// ---------------- stage B: out(f32) = / += w * (h @ downT) ----------------
// round-15 proven version: 128-row half-tiles, 2-phase counted-vmcnt dbuf.

template <bool STORE>
__global__ __launch_bounds__(256) void k_stageB(const unsigned short* __restrict__ h,
    const unsigned short* __restrict__ WdT, const unsigned short* __restrict__ SdT,
    const int* __restrict__ perm, const float* __restrict__ wrow,
    const int* __restrict__ te128,
    float* __restrict__ out, int t0, int row_base) {
  int tile = t0 + blockIdx.y;
  int e = te128[tile];
  if (e < 0) return;
  const unsigned short* Bd = (e < 8) ? WdT + (size_t)e * DIM * HID : SdT;
  int rows0 = tile * 128;
  int n0 = blockIdx.x * 128;

  __shared__ unsigned short As[2][128 * 64];
  __shared__ unsigned short Bs[2][128 * 64];

  int tid = threadIdx.x, lane = tid & 63, wv = tid >> 6;
  int wr = wv >> 1, wc = wv & 1;
  int rlo = lane >> 3;
  int koff = (((lane & 7) ^ rlo) * 8);
  int rsw = (lane & 7) << 4;

  f32x4 acc[4][4] = {};

  auto stage = [&](int b, int k0) {
    #pragma unroll
    for (int i = 0; i < 4; ++i) {
      int rb = i * 32 + wv * 8;
      int r = rb + rlo;
      gload16(h + (size_t)(rows0 - row_base + r) * HID + k0 + koff, (char*)As[b] + rb * 128);
      gload16(Bd + (size_t)(n0 + r) * HID + k0 + koff, (char*)Bs[b] + rb * 128);
    }
  };

  auto compute = [&](int b) {
    #pragma unroll
    for (int kk = 0; kk < 2; ++kk) {
      int kbyte = (kk * 64 + (lane >> 4) * 16) ^ rsw;
      bf16x8 a[4], bb[4];
      #pragma unroll
      for (int mi = 0; mi < 4; ++mi)
        a[mi] = *(const bf16x8*)((const char*)As[b] + (wr * 64 + mi * 16 + (lane & 15)) * 128 + kbyte);
      #pragma unroll
      for (int ni = 0; ni < 4; ++ni)
        bb[ni] = *(const bf16x8*)((const char*)Bs[b] + (wc * 64 + ni * 16 + (lane & 15)) * 128 + kbyte);
      #pragma unroll
      for (int mi = 0; mi < 4; ++mi) {
        #pragma unroll
        for (int ni = 0; ni < 4; ++ni)
          acc[mi][ni] = __builtin_amdgcn_mfma_f32_16x16x32_bf16(a[mi], bb[ni], acc[mi][ni], 0, 0, 0);
      }
    }
  };

  stage(0, 0);
  int cur = 0;
  for (int kb = 0; kb < HID / 64 - 1; ++kb) {
    stage(cur ^ 1, (kb + 1) * 64);
    __builtin_amdgcn_sched_barrier(0);
    asm volatile("s_waitcnt vmcnt(8)" ::: "memory");
    __builtin_amdgcn_s_barrier();
    __builtin_amdgcn_sched_barrier(0);
    __builtin_amdgcn_s_setprio(1);
    compute(cur);
    __builtin_amdgcn_s_setprio(0);
    __builtin_amdgcn_s_barrier();
    cur ^= 1;
  }
  asm volatile("s_waitcnt vmcnt(0)" ::: "memory");
  __builtin_amdgcn_s_barrier();
  __builtin_amdgcn_sched_barrier(0);
  compute(cur);

  #pragma unroll
  for (int mi = 0; mi < 4; ++mi) {
    #pragma unroll
    for (int j = 0; j < 4; ++j) {
      int rl = wr * 64 + mi * 16 + (lane >> 4) * 4 + j;
      int token = perm[rows0 + rl];
      float w = wrow[rows0 + rl];
      #pragma unroll
      for (int ni = 0; ni < 4; ++ni) {
        int col = n0 + wc * 64 + ni * 16 + (lane & 15);
        if (STORE) out[(size_t)token * DIM + col] = w * acc[mi][ni][j];
        else atomicAdd(&out[(size_t)token * DIM + col], w * acc[mi][ni][j]);
      }
    }
  }
}

// ---------------- aux loss (f32) ----------------

__global__ void k_aux(const float* __restrict__ f_cnt, const float* __restrict__ P_sum,
                      float* __restrict__ aux_out) {
  if (threadIdx.x == 0 && blockIdx.x == 0) {
    float a = 0.f;
    #pragma unroll
    for (int e = 0; e < 8; ++e) a += f_cnt[e] * P_sum[e];
    a *= 0.01f * 8.f / ((float)NTOK * (float)NTOK);
    aux_out[0] = a;
  }
}

// ---------------- launch ----------------

extern "C" void kernel_launch(void* const* d_in, const int* in_sizes, int n_in,
                              void* d_out, int out_size, void* d_ws, size_t ws_size,
                              hipStream_t stream) {
  const float* x  = (const float*)d_in[0];
  const float* gw = (const float*)d_in[1];
  const float* eg = (const float*)d_in[2];
  const float* eu = (const float*)d_in[3];
  const float* ed = (const float*)d_in[4];
  const float* sg = (const float*)d_in[5];
  const float* su = (const float*)d_in[6];
  const float* sd = (const float*)d_in[7];
  float* out = (float*)d_out;

  char* ws = (char*)d_ws;
  size_t off = 0;
  auto take = [&](size_t sz) { size_t o = off; off += (sz + 255) & ~(size_t)255; return o; };
  const size_t OFF_XB   = take((size_t)NTOK * DIM * 2);
  const size_t OFF_WI   = take((size_t)8 * NI * DIM * 2);   // interleaved gate|up
  const size_t OFF_SI   = take((size_t)NI * DIM * 2);
  const size_t OFF_WDT  = take((size_t)8 * HID * DIM * 2);
  const size_t OFF_SDT  = take((size_t)HID * DIM * 2);
  const size_t OFF_TI   = take((size_t)NTOK * 2 * 4);
  const size_t OFF_TW   = take((size_t)NTOK * 2 * 4);
  const size_t OFF_PERM = take((size_t)ROWS_CAP * 4);
  const size_t OFF_WROW = take((size_t)ROWS_CAP * 4);
  const size_t OFF_STATS= take(256);
  const size_t OFF_CURS = take(256);
  const size_t OFF_TE2  = take(TC256 * 4);
  const size_t OFF_TE1  = take(TC128 * 4);
  const size_t OFF_H    = off;   // h-buffer takes ALL remaining space

  const size_t TILE_H_BYTES = (size_t)256 * HID * 2;   // per 256-tile
  size_t avail = (ws_size > OFF_H) ? (ws_size - OFF_H) : 0;
  int G = (int)((avail / TILE_H_BYTES < (size_t)TC256) ? (avail / TILE_H_BYTES) : (size_t)TC256);
  if (G < 1) return;

  unsigned short* xb  = (unsigned short*)(ws + OFF_XB);
  unsigned short* WI  = (unsigned short*)(ws + OFF_WI);
  unsigned short* SI  = (unsigned short*)(ws + OFF_SI);
  unsigned short* WdT = (unsigned short*)(ws + OFF_WDT);
  unsigned short* SdT = (unsigned short*)(ws + OFF_SDT);
  int* top_idx        = (int*)(ws + OFF_TI);
  float* top_w        = (float*)(ws + OFF_TW);
  int* perm           = (int*)(ws + OFF_PERM);
  float* wrow         = (float*)(ws + OFF_WROW);
  int* counts         = (int*)(ws + OFF_STATS);
  float* f_cnt        = (float*)(ws + OFF_STATS + 32);
  float* P_sum        = (float*)(ws + OFF_STATS + 64);
  int* cursors        = (int*)(ws + OFF_CURS);
  int* te256          = (int*)(ws + OFF_TE2);
  int* te128          = (int*)(ws + OFF_TE1);
  unsigned short* hbuf = (unsigned short*)(ws + OFF_H);

  hipMemsetAsync(ws + OFF_STATS, 0, 256, stream);

  k_transpose_DH<<<dim3(HID / 64, DIM / 64, 18), 256, 0, stream>>>(
      eg, eu, sg, su, WI, SI);
  k_transpose_HD<<<dim3(DIM / 64, HID / 64, 9), 256, 0, stream>>>(
      ed, sd, WdT, SdT);

  k_router<<<512, 256, 0, stream>>>(x, gw, xb, top_idx, top_w, counts, f_cnt, P_sum);
  k_setup<<<1, 256, 0, stream>>>(counts, cursors, te256, te128, perm, wrow);
  k_scatter<<<NTOK * 2 / 256, 256, 0, stream>>>(top_idx, top_w, cursors, perm, wrow);

  for (int T0 = 0; T0 < TC256; T0 += G) {
    int nt = (TC256 - T0 < G) ? (TC256 - T0) : G;
    int row_base = T0 * 256;
    k_stageA<<<dim3(NI / 256, nt), 512, 0, stream>>>(xb, WI, SI, perm, te256,
                                                     hbuf, T0, row_base);
    int h0t = T0 * 2, hn = nt * 2;
    int ns = 0;
    if (h0t < 64) { ns = 64 - h0t; if (ns > hn) ns = hn; }
    int ne = hn - ns;
    if (ns > 0)
      k_stageB<true><<<dim3(DIM / 128, ns), 256, 0, stream>>>(hbuf, WdT, SdT, perm, wrow,
                                                              te128, out, h0t, row_base);
    if (ne > 0)
      k_stageB<false><<<dim3(DIM / 128, ne), 256, 0, stream>>>(hbuf, WdT, SdT, perm, wrow,
                                                               te128, out, h0t + ns, row_base);
  }

  k_aux<<<1, 64, 0, stream>>>(f_cnt, P_sum, out + (size_t)NTOK * DIM);
}

// Round 18
// 907.966 us; speedup vs baseline: 1.0593x; 1.0081x over previous
//
#include <hip/hip_runtime.h>
#include <hip/hip_bf16.h>

#define NTOK 8192
#define DIM  1024
#define HID  2816
#define NI   (2 * HID)          // interleaved gate|up rows per expert = 5632
#define ROWS_CAP 26880          // 8192 shared + 16384 assignments + 8*256 pad
#define TC256 104               // 32 shared 256-tiles + max 72 expert 256-tiles
#define TC128 208               // same in 128-half-tiles

typedef __bf16 bf16x8 __attribute__((ext_vector_type(8)));
typedef float  f32x4  __attribute__((ext_vector_type(4)));

__device__ __forceinline__ unsigned short f2bf(float f) {
  unsigned int x = __float_as_uint(f);
  unsigned int r = (x + 0x7fffu + ((x >> 16) & 1u)) >> 16;
  return (unsigned short)r;
}
__device__ __forceinline__ float gelu_erf(float g) {
  return 0.5f * g * (1.0f + erff(g * 0.70710678118654752f));
}

__device__ __forceinline__ void gload16(const void* g, void* l) {
  __builtin_amdgcn_global_load_lds(
      (__attribute__((address_space(1))) void*)(g),
      (__attribute__((address_space(3))) void*)(l), 16, 0, 0);
}

// ---- vectorized transpose: out[row(c)][r] = bf16(in[r][c]), 64x64 tile ----
__device__ __forceinline__ void transpose64(const float* __restrict__ in,
                                            unsigned short* __restrict__ out,
                                            int R, int C, int iloff) {
  __shared__ float t[64][65];
  int c0 = blockIdx.x * 64, r0 = blockIdx.y * 64;
  int tid = threadIdx.x;
  int lr = tid >> 4;            // 0..15
  int lc4 = (tid & 15) * 4;     // 0,4,...,60
  #pragma unroll
  for (int it = 0; it < 4; ++it) {
    int row = lr + it * 16;
    float4 v = *(const float4*)(in + (size_t)(r0 + row) * C + c0 + lc4);
    t[row][lc4] = v.x; t[row][lc4 + 1] = v.y;
    t[row][lc4 + 2] = v.z; t[row][lc4 + 3] = v.w;
  }
  __syncthreads();
  #pragma unroll
  for (int it = 0; it < 4; ++it) {
    int cloc = lr + it * 16;
    int c = c0 + cloc;
    int rowil = (iloff < 0) ? c : (((c >> 4) << 5) + (c & 15) + iloff);
    ushort4 w = make_ushort4(f2bf(t[lc4][cloc]), f2bf(t[lc4 + 1][cloc]),
                             f2bf(t[lc4 + 2][cloc]), f2bf(t[lc4 + 3][cloc]));
    *(ushort4*)(out + (size_t)rowil * R + r0 + lc4) = w;
  }
}

__global__ __launch_bounds__(256) void k_transpose_DH(
    const float* __restrict__ eg, const float* __restrict__ eu,
    const float* __restrict__ sg, const float* __restrict__ su,
    unsigned short* __restrict__ WI, unsigned short* __restrict__ SI) {
  int z = blockIdx.z;
  const float* in; unsigned short* out; int off;
  if (z < 8)        { in = eg + (size_t)z * DIM * HID;       out = WI + (size_t)z * NI * DIM; off = 0; }
  else if (z < 16)  { in = eu + (size_t)(z - 8) * DIM * HID; out = WI + (size_t)(z - 8) * NI * DIM; off = 16; }
  else if (z == 16) { in = sg; out = SI; off = 0; }
  else              { in = su; out = SI; off = 16; }
  transpose64(in, out, DIM, HID, off);
}

__global__ __launch_bounds__(256) void k_transpose_HD(
    const float* __restrict__ ed, const float* __restrict__ sd,
    unsigned short* __restrict__ WdT, unsigned short* __restrict__ SdT) {
  int z = blockIdx.z;
  const float* in; unsigned short* out;
  if (z < 8) { in = ed + (size_t)z * HID * DIM; out = WdT + (size_t)z * HID * DIM; }
  else       { in = sd; out = SdT; }
  transpose64(in, out, HID, DIM, -1);
}

// ---------------- router + fused x->bf16 cast (block-reduced stats) ----------------

__global__ __launch_bounds__(256) void k_router(const float* __restrict__ x,
                                                const float* __restrict__ gw,
                                                unsigned short* __restrict__ xb,
                                                int* __restrict__ top_idx,
                                                float* __restrict__ top_w,
                                                int* __restrict__ counts,
                                                float* __restrict__ f_cnt,
                                                float* __restrict__ P_sum) {
  __shared__ float s_p[8];
  __shared__ int   s_cnt[8];
  __shared__ int   s_f[8];
  int tid = threadIdx.x;
  if (tid < 8) { s_p[tid] = 0.f; s_cnt[tid] = 0; s_f[tid] = 0; }
  __syncthreads();

  int lane = tid & 63, wv = tid >> 6;
  float ploc[8] = {0,0,0,0,0,0,0,0};
  int   cloc[8] = {0,0,0,0,0,0,0,0};
  int   floc[8] = {0,0,0,0,0,0,0,0};

  for (int t = blockIdx.x * 4 + wv; t < NTOK; t += 2048) {
    const float4* xr = (const float4*)(x + (size_t)t * DIM) + lane * 4;
    float4 v0 = xr[0], v1 = xr[1], v2 = xr[2], v3 = xr[3];
    float xv[16] = {v0.x, v0.y, v0.z, v0.w, v1.x, v1.y, v1.z, v1.w,
                    v2.x, v2.y, v2.z, v2.w, v3.x, v3.y, v3.z, v3.w};
    ushort4* xw = (ushort4*)(xb + (size_t)t * DIM + lane * 16);
    #pragma unroll
    for (int q = 0; q < 4; ++q)
      xw[q] = make_ushort4(f2bf(xv[q * 4]), f2bf(xv[q * 4 + 1]),
                           f2bf(xv[q * 4 + 2]), f2bf(xv[q * 4 + 3]));
    float acc[8] = {0.f,0.f,0.f,0.f,0.f,0.f,0.f,0.f};
    #pragma unroll
    for (int i = 0; i < 16; ++i) {
      const float* g = gw + (size_t)(lane * 16 + i) * 8;
      #pragma unroll
      for (int e = 0; e < 8; ++e) acc[e] += xv[i] * g[e];
    }
    #pragma unroll
    for (int e = 0; e < 8; ++e) {
      #pragma unroll
      for (int off = 32; off > 0; off >>= 1)
        acc[e] += __shfl_xor(acc[e], off, 64);
    }
    if (lane == 0) {
      int i1 = 0; float l1 = acc[0];
      #pragma unroll
      for (int e = 1; e < 8; ++e) if (acc[e] > l1) { l1 = acc[e]; i1 = e; }
      int i2 = -1; float l2 = -3.0e38f;
      #pragma unroll
      for (int e = 0; e < 8; ++e) if (e != i1 && acc[e] > l2) { l2 = acc[e]; i2 = e; }
      float e2 = expf(l2 - l1);
      float inv12 = 1.0f / (1.0f + e2);
      top_idx[2 * t] = i1; top_idx[2 * t + 1] = i2;
      top_w[2 * t] = inv12; top_w[2 * t + 1] = e2 * inv12;
      float s = 0.f, p[8];
      #pragma unroll
      for (int e = 0; e < 8; ++e) { p[e] = expf(acc[e] - l1); s += p[e]; }
      float invs = 1.0f / s;
      #pragma unroll
      for (int e = 0; e < 8; ++e) {
        ploc[e] += p[e] * invs;
        cloc[e] += (e == i1) + (e == i2);
        floc[e] += (e == i1);
      }
    }
  }
  if (lane == 0) {
    #pragma unroll
    for (int e = 0; e < 8; ++e) {
      atomicAdd(&s_p[e], ploc[e]);
      atomicAdd(&s_cnt[e], cloc[e]);
      atomicAdd(&s_f[e], floc[e]);
    }
  }
  __syncthreads();
  if (tid < 8) {
    atomicAdd(&P_sum[tid], s_p[tid]);
    atomicAdd(&counts[tid], s_cnt[tid]);
    atomicAdd(&f_cnt[tid], (float)s_f[tid]);
  }
}

// ---------------- segment setup (256-row padding) / scatter ----------------

__global__ __launch_bounds__(256) void k_setup(const int* __restrict__ counts,
                                               int* __restrict__ cursors,
                                               int* __restrict__ te256,
                                               int* __restrict__ te128,
                                               int* __restrict__ perm,
                                               float* __restrict__ wrow) {
  int t = threadIdx.x;
  for (int r = t; r < ROWS_CAP; r += 256) {
    perm[r] = (r < NTOK) ? r : 0;
    wrow[r] = (r < NTOK) ? 1.0f : 0.0f;
  }
  if (t == 0) {
    int so[8], pe[8];
    int cur = NTOK;
    for (int e = 0; e < 8; ++e) {
      so[e] = cur;
      pe[e] = ((counts[e] + 255) >> 8) << 8;     // pad to 256 rows
      cur += pe[e];
    }
    for (int e = 0; e < 8; ++e) cursors[e] = so[e];
    for (int T = 0; T < TC256; ++T) {
      int r0 = T << 8;
      int ex;
      if (T < NTOK / 256) ex = 8;                // shared expert
      else if (r0 < cur) {
        ex = 0;
        for (int e = 0; e < 8; ++e) if (r0 >= so[e] && r0 < so[e] + pe[e]) ex = e;
      } else ex = -1;
      te256[T] = ex;
    }
    for (int ht = 0; ht < TC128; ++ht) {
      int r0 = ht << 7;
      int ex;
      if (ht < NTOK / 128) ex = 8;
      else if (r0 < cur) {
        ex = 0;
        for (int e = 0; e < 8; ++e) if (r0 >= so[e] && r0 < so[e] + pe[e]) ex = e;
      } else ex = -1;
      te128[ht] = ex;
    }
  }
}

__global__ __launch_bounds__(256) void k_scatter(const int* __restrict__ top_idx,
                                                 const float* __restrict__ top_w,
                                                 int* __restrict__ cursors,
                                                 int* __restrict__ perm,
                                                 float* __restrict__ wrow) {
  int i = blockIdx.x * 256 + threadIdx.x;
  if (i < NTOK * 2) {
    int e = top_idx[i];
    float w = top_w[i];
    int slot = atomicAdd(&cursors[e], 1);
    perm[slot] = i >> 1;
    wrow[slot] = w;
  }
}

// ---------------- stage A: h = gelu(x@gate) * (x@up) -------------------------
// 256-row tiles, 512 threads (8 waves 2x4), interleaved gate|up B.
// 4-phase schedule, prefetch ordered BY NEED (B first): B0B1@q0, B2B3@q1,
// A0A1@q2, A2A3@q3. Boundary drains vmcnt(1) (A3 stays in flight); A3 is
// published by vmcnt(4) folded into the phase-1->2 barrier.

__global__ __launch_bounds__(512) void k_stageA(const unsigned short* __restrict__ xb,
    const unsigned short* __restrict__ WI, const unsigned short* __restrict__ SI,
    const int* __restrict__ perm, const int* __restrict__ te256,
    unsigned short* __restrict__ h, int T0, int row_base) {
  int T = T0 + blockIdx.y;
  int e = te256[T];
  if (e < 0) return;
  const unsigned short* B = (e < 8) ? WI + (size_t)e * NI * DIM : SI;
  int rows0 = T * 256;
  int c0i = blockIdx.x * 256;     // interleaved-col base

  __shared__ unsigned short As[2][256 * 64];   // 32 KB each
  __shared__ unsigned short Bs[2][256 * 64];

  int tid = threadIdx.x, lane = tid & 63, w = tid >> 6;
  int wr = w >> 2, wc = w & 3;
  int rlo = lane >> 3;
  int koff = ((lane & 7) ^ rlo) * 8;           // pre-swizzled source column
  int fr = lane & 15;
  int kby0 = ((lane >> 4) * 16) ^ ((lane & 7) << 4);
  int kby1 = (64 + (lane >> 4) * 16) ^ ((lane & 7) << 4);

  int prow[4];
  #pragma unroll
  for (int i = 0; i < 4; ++i) prow[i] = perm[rows0 + i * 64 + w * 8 + rlo];
  const unsigned short* bsrc[4];
  #pragma unroll
  for (int i = 0; i < 4; ++i)
    bsrc[i] = B + (size_t)(c0i + i * 64 + w * 8 + rlo) * DIM + koff;

  f32x4 acc[8][4] = {};

  #pragma unroll
  for (int i = 0; i < 4; ++i)
    gload16(xb + (size_t)prow[i] * DIM + koff, (char*)As[0] + (i * 64 + w * 8) * 128);
  #pragma unroll
  for (int i = 0; i < 4; ++i)
    gload16(bsrc[i], (char*)Bs[0] + (i * 64 + w * 8) * 128);
  asm volatile("s_waitcnt vmcnt(0)" ::: "memory");
  __builtin_amdgcn_s_barrier();
  __builtin_amdgcn_sched_barrier(0);

  int cur = 0;
  for (int kb = 0; kb < DIM / 64; ++kb) {
    const char* Ab = (const char*)As[cur];
    const char* Bb = (const char*)Bs[cur];
    char* An = (char*)As[cur ^ 1];
    char* Bn = (char*)Bs[cur ^ 1];
    int k1 = (kb + 1) * 64;
    bool pf = (kb < DIM / 64 - 1);
    bf16x8 bfr[4][2];

    #pragma unroll
    for (int q = 0; q < 4; ++q) {
      bf16x8 a[2][2];
      #pragma unroll
      for (int m = 0; m < 2; ++m) {
        const char* ar = Ab + (wr * 128 + (2 * q + m) * 16 + fr) * 128;
        a[m][0] = *(const bf16x8*)(ar + kby0);
        a[m][1] = *(const bf16x8*)(ar + kby1);
      }
      if (q == 0) {
        #pragma unroll
        for (int ni = 0; ni < 4; ++ni) {
          const char* br = Bb + (wc * 64 + ni * 16 + fr) * 128;
          bfr[ni][0] = *(const bf16x8*)(br + kby0);
          bfr[ni][1] = *(const bf16x8*)(br + kby1);
        }
      }
      // prefetch in need-order: B first (consumed at next phase 0), A last.
      if (pf) {
        if (q == 0) {
          gload16(bsrc[0] + k1, Bn + (0 * 64 + w * 8) * 128);
          gload16(bsrc[1] + k1, Bn + (1 * 64 + w * 8) * 128);
        } else if (q == 1) {
          gload16(bsrc[2] + k1, Bn + (2 * 64 + w * 8) * 128);
          gload16(bsrc[3] + k1, Bn + (3 * 64 + w * 8) * 128);
        } else if (q == 2) {
          gload16(xb + (size_t)prow[0] * DIM + k1 + koff, An + (0 * 64 + w * 8) * 128);
          gload16(xb + (size_t)prow[1] * DIM + k1 + koff, An + (1 * 64 + w * 8) * 128);
        } else {
          gload16(xb + (size_t)prow[2] * DIM + k1 + koff, An + (2 * 64 + w * 8) * 128);
          gload16(xb + (size_t)prow[3] * DIM + k1 + koff, An + (3 * 64 + w * 8) * 128);
        }
      }
      __builtin_amdgcn_s_barrier();
      __builtin_amdgcn_s_setprio(1);
      #pragma unroll
      for (int kk = 0; kk < 2; ++kk) {
        #pragma unroll
        for (int m = 0; m < 2; ++m) {
          #pragma unroll
          for (int ni = 0; ni < 4; ++ni)
            acc[2 * q + m][ni] = __builtin_amdgcn_mfma_f32_16x16x32_bf16(
                a[m][kk], bfr[ni][kk], acc[2 * q + m][ni], 0, 0, 0);
        }
      }
      __builtin_amdgcn_s_setprio(0);
      if (q == 1) {
        // publish previous iteration's A3 band (rows 192-255) before phase 2
        // reads it; leaves this iteration's B0-B3 prefetches in flight.
        asm volatile("s_waitcnt vmcnt(4)" ::: "memory");
        __builtin_amdgcn_s_barrier();
      } else if (q < 3) {
        __builtin_amdgcn_s_barrier();
      } else {
        // boundary: drain through A2 (vmcnt(1) leaves A3 in flight).
        asm volatile("s_waitcnt vmcnt(1)" ::: "memory");
        __builtin_amdgcn_s_barrier();
        __builtin_amdgcn_sched_barrier(0);
      }
    }
    cur ^= 1;
  }

  #pragma unroll
  for (int mi = 0; mi < 8; ++mi) {
    #pragma unroll
    for (int p = 0; p < 2; ++p) {
      #pragma unroll
      for (int j = 0; j < 4; ++j) {
        int rg = rows0 - row_base + wr * 128 + mi * 16 + (lane >> 4) * 4 + j;
        int cg = blockIdx.x * 128 + wc * 32 + p * 16 + fr;
        float g = acc[mi][2 * p][j];
        float u = acc[mi][2 * p + 1][j];
        h[(size_t)rg * HID + cg] = f2bf(gelu_erf(g) * u);
      }
    }
  }
}

// ---------------- stage B: out(f32) = / += w * (h @ downT) ----------------
// round-15 proven version: 128-row half-tiles, 2-phase counted-vmcnt dbuf.

template <bool STORE>
__global__ __launch_bounds__(256) void k_stageB(const unsigned short* __restrict__ h,
    const unsigned short* __restrict__ WdT, const unsigned short* __restrict__ SdT,
    const int* __restrict__ perm, const float* __restrict__ wrow,
    const int* __restrict__ te128,
    float* __restrict__ out, int t0, int row_base) {
  int tile = t0 + blockIdx.y;
  int e = te128[tile];
  if (e < 0) return;
  const unsigned short* Bd = (e < 8) ? WdT + (size_t)e * DIM * HID : SdT;
  int rows0 = tile * 128;
  int n0 = blockIdx.x * 128;

  __shared__ unsigned short As[2][128 * 64];
  __shared__ unsigned short Bs[2][128 * 64];

  int tid = threadIdx.x, lane = tid & 63, wv = tid >> 6;
  int wr = wv >> 1, wc = wv & 1;
  int rlo = lane >> 3;
  int koff = (((lane & 7) ^ rlo) * 8);
  int rsw = (lane & 7) << 4;

  f32x4 acc[4][4] = {};

  auto stage = [&](int b, int k0) {
    #pragma unroll
    for (int i = 0; i < 4; ++i) {
      int rb = i * 32 + wv * 8;
      int r = rb + rlo;
      gload16(h + (size_t)(rows0 - row_base + r) * HID + k0 + koff, (char*)As[b] + rb * 128);
      gload16(Bd + (size_t)(n0 + r) * HID + k0 + koff, (char*)Bs[b] + rb * 128);
    }
  };

  auto compute = [&](int b) {
    #pragma unroll
    for (int kk = 0; kk < 2; ++kk) {
      int kbyte = (kk * 64 + (lane >> 4) * 16) ^ rsw;
      bf16x8 a[4], bb[4];
      #pragma unroll
      for (int mi = 0; mi < 4; ++mi)
        a[mi] = *(const bf16x8*)((const char*)As[b] + (wr * 64 + mi * 16 + (lane & 15)) * 128 + kbyte);
      #pragma unroll
      for (int ni = 0; ni < 4; ++ni)
        bb[ni] = *(const bf16x8*)((const char*)Bs[b] + (wc * 64 + ni * 16 + (lane & 15)) * 128 + kbyte);
      #pragma unroll
      for (int mi = 0; mi < 4; ++mi) {
        #pragma unroll
        for (int ni = 0; ni < 4; ++ni)
          acc[mi][ni] = __builtin_amdgcn_mfma_f32_16x16x32_bf16(a[mi], bb[ni], acc[mi][ni], 0, 0, 0);
      }
    }
  };

  stage(0, 0);
  int cur = 0;
  for (int kb = 0; kb < HID / 64 - 1; ++kb) {
    stage(cur ^ 1, (kb + 1) * 64);
    __builtin_amdgcn_sched_barrier(0);
    asm volatile("s_waitcnt vmcnt(8)" ::: "memory");
    __builtin_amdgcn_s_barrier();
    __builtin_amdgcn_sched_barrier(0);
    __builtin_amdgcn_s_setprio(1);
    compute(cur);
    __builtin_amdgcn_s_setprio(0);
    __builtin_amdgcn_s_barrier();
    cur ^= 1;
  }
  asm volatile("s_waitcnt vmcnt(0)" ::: "memory");
  __builtin_amdgcn_s_barrier();
  __builtin_amdgcn_sched_barrier(0);
  compute(cur);

  #pragma unroll
  for (int mi = 0; mi < 4; ++mi) {
    #pragma unroll
    for (int j = 0; j < 4; ++j) {
      int rl = wr * 64 + mi * 16 + (lane >> 4) * 4 + j;
      int token = perm[rows0 + rl];
      float w = wrow[rows0 + rl];
      #pragma unroll
      for (int ni = 0; ni < 4; ++ni) {
        int col = n0 + wc * 64 + ni * 16 + (lane & 15);
        if (STORE) out[(size_t)token * DIM + col] = w * acc[mi][ni][j];
        else atomicAdd(&out[(size_t)token * DIM + col], w * acc[mi][ni][j]);
      }
    }
  }
}

// ---------------- aux loss (f32) ----------------

__global__ void k_aux(const float* __restrict__ f_cnt, const float* __restrict__ P_sum,
                      float* __restrict__ aux_out) {
  if (threadIdx.x == 0 && blockIdx.x == 0) {
    float a = 0.f;
    #pragma unroll
    for (int e = 0; e < 8; ++e) a += f_cnt[e] * P_sum[e];
    a *= 0.01f * 8.f / ((float)NTOK * (float)NTOK);
    aux_out[0] = a;
  }
}

// ---------------- launch ----------------

extern "C" void kernel_launch(void* const* d_in, const int* in_sizes, int n_in,
                              void* d_out, int out_size, void* d_ws, size_t ws_size,
                              hipStream_t stream) {
  const float* x  = (const float*)d_in[0];
  const float* gw = (const float*)d_in[1];
  const float* eg = (const float*)d_in[2];
  const float* eu = (const float*)d_in[3];
  const float* ed = (const float*)d_in[4];
  const float* sg = (const float*)d_in[5];
  const float* su = (const float*)d_in[6];
  const float* sd = (const float*)d_in[7];
  float* out = (float*)d_out;

  char* ws = (char*)d_ws;
  size_t off = 0;
  auto take = [&](size_t sz) { size_t o = off; off += (sz + 255) & ~(size_t)255; return o; };
  const size_t OFF_XB   = take((size_t)NTOK * DIM * 2);
  const size_t OFF_WI   = take((size_t)8 * NI * DIM * 2);   // interleaved gate|up
  const size_t OFF_SI   = take((size_t)NI * DIM * 2);
  const size_t OFF_WDT  = take((size_t)8 * HID * DIM * 2);
  const size_t OFF_SDT  = take((size_t)HID * DIM * 2);
  const size_t OFF_TI   = take((size_t)NTOK * 2 * 4);
  const size_t OFF_TW   = take((size_t)NTOK * 2 * 4);
  const size_t OFF_PERM = take((size_t)ROWS_CAP * 4);
  const size_t OFF_WROW = take((size_t)ROWS_CAP * 4);
  const size_t OFF_STATS= take(256);
  const size_t OFF_CURS = take(256);
  const size_t OFF_TE2  = take(TC256 * 4);
  const size_t OFF_TE1  = take(TC128 * 4);
  const size_t OFF_H    = off;   // h-buffer takes ALL remaining space

  const size_t TILE_H_BYTES = (size_t)256 * HID * 2;   // per 256-tile
  size_t avail = (ws_size > OFF_H) ? (ws_size - OFF_H) : 0;
  int G = (int)((avail / TILE_H_BYTES < (size_t)TC256) ? (avail / TILE_H_BYTES) : (size_t)TC256);
  if (G < 1) return;

  unsigned short* xb  = (unsigned short*)(ws + OFF_XB);
  unsigned short* WI  = (unsigned short*)(ws + OFF_WI);
  unsigned short* SI  = (unsigned short*)(ws + OFF_SI);
  unsigned short* WdT = (unsigned short*)(ws + OFF_WDT);
  unsigned short* SdT = (unsigned short*)(ws + OFF_SDT);
  int* top_idx        = (int*)(ws + OFF_TI);
  float* top_w        = (float*)(ws + OFF_TW);
  int* perm           = (int*)(ws + OFF_PERM);
  float* wrow         = (float*)(ws + OFF_WROW);
  int* counts         = (int*)(ws + OFF_STATS);
  float* f_cnt        = (float*)(ws + OFF_STATS + 32);
  float* P_sum        = (float*)(ws + OFF_STATS + 64);
  int* cursors        = (int*)(ws + OFF_CURS);
  int* te256          = (int*)(ws + OFF_TE2);
  int* te128          = (int*)(ws + OFF_TE1);
  unsigned short* hbuf = (unsigned short*)(ws + OFF_H);

  hipMemsetAsync(ws + OFF_STATS, 0, 256, stream);

  k_transpose_DH<<<dim3(HID / 64, DIM / 64, 18), 256, 0, stream>>>(
      eg, eu, sg, su, WI, SI);
  k_transpose_HD<<<dim3(DIM / 64, HID / 64, 9), 256, 0, stream>>>(
      ed, sd, WdT, SdT);

  k_router<<<512, 256, 0, stream>>>(x, gw, xb, top_idx, top_w, counts, f_cnt, P_sum);
  k_setup<<<1, 256, 0, stream>>>(counts, cursors, te256, te128, perm, wrow);
  k_scatter<<<NTOK * 2 / 256, 256, 0, stream>>>(top_idx, top_w, cursors, perm, wrow);

  for (int T0 = 0; T0 < TC256; T0 += G) {
    int nt = (TC256 - T0 < G) ? (TC256 - T0) : G;
    int row_base = T0 * 256;
    k_stageA<<<dim3(NI / 256, nt), 512, 0, stream>>>(xb, WI, SI, perm, te256,
                                                     hbuf, T0, row_base);
    int h0t = T0 * 2, hn = nt * 2;
    int ns = 0;
    if (h0t < 64) { ns = 64 - h0t; if (ns > hn) ns = hn; }
    int ne = hn - ns;
    if (ns > 0)
      k_stageB<true><<<dim3(DIM / 128, ns), 256, 0, stream>>>(hbuf, WdT, SdT, perm, wrow,
                                                              te128, out, h0t, row_base);
    if (ne > 0)
      k_stageB<false><<<dim3(DIM / 128, ne), 256, 0, stream>>>(hbuf, WdT, SdT, perm, wrow,
                                                               te128, out, h0t + ns, row_base);
  }

  k_aux<<<1, 64, 0, stream>>>(f_cnt, P_sum, out + (size_t)NTOK * DIM);
}